// Round 3
// baseline (324.063 us; speedup 1.0000x reference)
//
#include <hip/hip_runtime.h>
#include <cstdint>

#define N_SAMPLES 16384
#define DIM 2048
#define PDIM 256
#define NB 32
#define NL 100
#define NSEG (NB * NL)

typedef float floatx4 __attribute__((ext_vector_type(4)));
typedef __bf16 bf16x8 __attribute__((ext_vector_type(8)));

__device__ __forceinline__ unsigned short f32_to_bf16(float f) {
    unsigned int u = __float_as_uint(f);
    u += 0x7fffu + ((u >> 16) & 1u);   // round-to-nearest-even
    return (unsigned short)(u >> 16);
}
__device__ __forceinline__ unsigned int pack_bf16x2(float a, float b) {
    return (unsigned int)f32_to_bf16(a) | ((unsigned int)f32_to_bf16(b) << 16);
}

// ---------------------------------------------------------------------------
// prep: weights -> bf16, bias sum, seg index, zero SW2 (for split-K atomics)
// ---------------------------------------------------------------------------
__global__ __launch_bounds__(256) void prep_kernel(
    const float* __restrict__ W1w, const float* __restrict__ W1b,
    const float* __restrict__ W2w, const float* __restrict__ W2b,
    const int* __restrict__ label, const int* __restrict__ lbatch,
    unsigned short* __restrict__ W1bf, unsigned short* __restrict__ W2bf,
    float* __restrict__ bias, int* __restrict__ seg,
    float* __restrict__ SW2)
{
    int i = blockIdx.x * 256 + threadIdx.x;   // grid = PDIM*DIM threads
    W1bf[i] = f32_to_bf16(W1w[i]);
    W2bf[i] = f32_to_bf16(W2w[i]);
    if (i < PDIM) bias[i] = W1b[i] + W2b[i];
    if (i < N_SAMPLES) seg[i] = lbatch[i] * NL + label[i];
    if (i < NSEG * PDIM / 2) ((float2*)SW2)[i] = make_float2(0.f, 0.f);
}

// ---------------------------------------------------------------------------
// scan: single WG. Builds the histogram in LDS (16384 seg reads, LDS atomics)
// then exclusive prefix over 3200 bins -> offs[3201], cursor copy.
// Replaces the former separate hist_kernel + global hist buffer.
// ---------------------------------------------------------------------------
#define SCAN_BPT 13   // 256*13 = 3328 >= 3200
__global__ __launch_bounds__(256) void scan_kernel(
    const int* __restrict__ seg, int* __restrict__ offs, int* __restrict__ cursor)
{
    __shared__ int lh[NSEG];   // 12.8 KB LDS histogram
    __shared__ int ps[256];
    const int t = threadIdx.x;
    for (int i = t; i < NSEG; i += 256) lh[i] = 0;
    __syncthreads();
    #pragma unroll 4
    for (int i = t; i < N_SAMPLES; i += 256)
        atomicAdd(&lh[seg[i]], 1);
    __syncthreads();

    int local = 0;
    #pragma unroll
    for (int k = 0; k < SCAN_BPT; ++k) {
        int bin = t * SCAN_BPT + k;
        if (bin < NSEG) local += lh[bin];
    }
    ps[t] = local;
    __syncthreads();
    for (int d = 1; d < 256; d <<= 1) {
        int v = (t >= d) ? ps[t - d] : 0;
        __syncthreads();
        ps[t] += v;
        __syncthreads();
    }
    int run = ps[t] - local;   // exclusive start for this thread's range
    #pragma unroll
    for (int k = 0; k < SCAN_BPT; ++k) {
        int bin = t * SCAN_BPT + k;
        if (bin < NSEG) {
            offs[bin] = run;
            cursor[bin] = run;
            run += lh[bin];
        }
    }
    if (t == 255) offs[NSEG] = ps[255];   // = N_SAMPLES
}

__global__ __launch_bounds__(256) void scatter_kernel(
    const int* __restrict__ seg, int* __restrict__ cursor, int* __restrict__ perm)
{
    int i = blockIdx.x * 256 + threadIdx.x;
    int pos = atomicAdd(&cursor[seg[i]], 1);
    perm[pos] = i;
}

// ---------------------------------------------------------------------------
// segsum: wave = (segment, 512-col chunk), lane = 8 floats. 8-row batches
// put 16 independent 16B loads in flight before the first use. Per-segment
// sums written directly in bf16 (f32 accumulation, one rounding); the LOO
// mean is recovered after the small GEMM by linearity (finalize_kernel).
// ---------------------------------------------------------------------------
__global__ __launch_bounds__(256) void segsum_kernel(
    const float* __restrict__ x, const int* __restrict__ perm,
    const int* __restrict__ offs,
    unsigned short* __restrict__ xb, unsigned short* __restrict__ sumb)
{
    const int tid = threadIdx.x;
    const int w = tid >> 6, lane = tid & 63;
    const int s = blockIdx.y * 4 + w;              // segment, 0..3199
    const int c = blockIdx.x * 512 + lane * 8;     // 8 consecutive floats/lane
    const int beg = offs[s], end = offs[s + 1];

    floatx4 sum0 = {0.f, 0.f, 0.f, 0.f};
    floatx4 sum1 = {0.f, 0.f, 0.f, 0.f};
    for (int base = beg; base < end; base += 64) {
        int p = (base + lane < end) ? perm[base + lane] : 0;
        const int n = min(end - base, 64);
        for (int j0 = 0; j0 < n; j0 += 8) {
            int rr[8];
            floatx4 v0[8], v1[8];
            #pragma unroll
            for (int j = 0; j < 8; ++j) {
                rr[j] = __shfl(p, min(j0 + j, n - 1));   // clamp: dup loads hit L1
                const float* px = &x[(size_t)rr[j] * DIM + c];
                v0[j] = *(const floatx4*)px;
                v1[j] = *(const floatx4*)(px + 4);
            }
            #pragma unroll
            for (int j = 0; j < 8; ++j) {
                if (j < n - j0) {
                    sum0 += v0[j];
                    sum1 += v1[j];
                    uint4 o;
                    o.x = pack_bf16x2(v0[j][0], v0[j][1]);
                    o.y = pack_bf16x2(v0[j][2], v0[j][3]);
                    o.z = pack_bf16x2(v1[j][0], v1[j][1]);
                    o.w = pack_bf16x2(v1[j][2], v1[j][3]);
                    *(uint4*)&xb[(size_t)rr[j] * DIM + c] = o;   // 16B/lane
                }
            }
        }
    }
    uint4 so;
    so.x = pack_bf16x2(sum0[0], sum0[1]);
    so.y = pack_bf16x2(sum0[2], sum0[3]);
    so.z = pack_bf16x2(sum1[0], sum1[1]);
    so.w = pack_bf16x2(sum1[2], sum1[3]);
    *(uint4*)&sumb[(size_t)s * DIM + c] = so;   // bf16 segment sums, 16B/lane
}

// ---------------------------------------------------------------------------
// finalize: SW2[s,col] <- (BW2[b,col] - SW2[s,col]) / dc   (in place)
// BW2[b] = sum over the batch's 100 label-rows of SW2 (linearity of the GEMM),
// dc = batch count - segment count (zero-guarded like the reference).
// ---------------------------------------------------------------------------
__global__ __launch_bounds__(256) void finalize_kernel(
    float* __restrict__ SW2, const int* __restrict__ offs)
{
    const int b = blockIdx.x;        // 0..31
    const int col = threadIdx.x;     // 0..255
    const int cb = offs[(b + 1) * NL] - offs[b * NL];   // batch count
    float tot = 0.f;
    #pragma unroll 4
    for (int l = 0; l < NL; ++l)
        tot += SW2[(size_t)(b * NL + l) * PDIM + col];
    for (int l = 0; l < NL; ++l) {
        const int s = b * NL + l;
        const int dc = cb - (offs[s + 1] - offs[s]);
        const float v = SW2[(size_t)s * PDIM + col];
        SW2[(size_t)s * PDIM + col] = (dc > 0) ? (tot - v) / (float)dc : 0.f;
    }
}

// ---------------------------------------------------------------------------
// GEMM: C[M,256] = A[M,K]_bf16 @ B[256,K]_bf16^T.
// 2-phase double-buffered K-loop (T3-minimum): prologue-stage buf0, then per
// tile {stage(next) -> ds_read+MFMA(cur) -> ONE __syncthreads}. Staging
// latency hides under the MFMA phase; one barrier per K-step instead of two.
// KSPLIT>1: blockIdx.z = K-slice, epilogue atomicAdd (C pre-zeroed).
// FUSE: += bias[col] + add[seg[row]*256 + col]
// ---------------------------------------------------------------------------
template<int BM, int BN, int WR, int WC, bool FUSE, int KSPLIT>
__global__ __launch_bounds__(256) void gemm_bt_kernel(
    const unsigned short* __restrict__ A,
    const unsigned short* __restrict__ B,
    float* __restrict__ C,
    const float* __restrict__ bias,
    const float* __restrict__ add,
    const int* __restrict__ seg,
    int K)
{
    constexpr int SM = BM / WR, SN = BN / WC;
    constexpr int FM = SM / 16, FN = SN / 16;
    __shared__ __align__(16) unsigned short ldsA[2][BM * 32];
    __shared__ __align__(16) unsigned short ldsB[2][BN * 32];
    const int tid = threadIdx.x;
    const int lane = tid & 63;
    const int wave = tid >> 6;
    const int wr = wave / WC, wc = wave % WC;
    const int quad = lane >> 4, l15 = lane & 15;
    const int m0 = blockIdx.x * BM;
    const int n0 = blockIdx.y * BN;
    const int kpw = K / KSPLIT;
    const int k0 = blockIdx.z * kpw;
    const int srow = lane >> 2, schunk = lane & 3;

    floatx4 acc[FM][FN];
    #pragma unroll
    for (int i = 0; i < FM; ++i)
        #pragma unroll
        for (int j = 0; j < FN; ++j) acc[i][j] = (floatx4){0.f, 0.f, 0.f, 0.f};

    const unsigned short* Abase = A + (size_t)(m0 + srow) * K + schunk * 8;
    const unsigned short* Bbase = B + (size_t)(n0 + srow) * K + schunk * 8;

    auto stage = [&](int buf, int kk) {
        #pragma unroll
        for (int ch = wave; ch < BM / 16; ch += 4)
            __builtin_amdgcn_global_load_lds(
                (const __attribute__((address_space(1))) void*)(Abase + (size_t)ch * 16 * K + kk),
                (__attribute__((address_space(3))) void*)&ldsA[buf][ch * 16 * 32], 16, 0, 0);
        #pragma unroll
        for (int ch = wave; ch < BN / 16; ch += 4)
            __builtin_amdgcn_global_load_lds(
                (const __attribute__((address_space(1))) void*)(Bbase + (size_t)ch * 16 * K + kk),
                (__attribute__((address_space(3))) void*)&ldsB[buf][ch * 16 * 32], 16, 0, 0);
    };

    const int nt = kpw / 32;
    stage(0, k0);
    __syncthreads();                       // buf0 ready (vmcnt drained)

    for (int t = 0; t < nt; ++t) {
        const int cur = t & 1;
        if (t + 1 < nt) stage(cur ^ 1, k0 + (t + 1) * 32);   // prefetch in flight

        bf16x8 af[FM], bfr[FN];
        #pragma unroll
        for (int mi = 0; mi < FM; ++mi)
            af[mi] = *(const bf16x8*)&ldsA[cur][(wr * SM + mi * 16 + l15) * 32 + quad * 8];
        #pragma unroll
        for (int ni = 0; ni < FN; ++ni)
            bfr[ni] = *(const bf16x8*)&ldsB[cur][(wc * SN + ni * 16 + l15) * 32 + quad * 8];
        #pragma unroll
        for (int mi = 0; mi < FM; ++mi)
            #pragma unroll
            for (int ni = 0; ni < FN; ++ni)
                acc[mi][ni] = __builtin_amdgcn_mfma_f32_16x16x32_bf16(
                    af[mi], bfr[ni], acc[mi][ni], 0, 0, 0);

        __syncthreads();                   // drains prefetch; next buf ready
    }

    #pragma unroll
    for (int mi = 0; mi < FM; ++mi) {
        const int rbase = m0 + wr * SM + mi * 16 + quad * 4;
        #pragma unroll
        for (int ni = 0; ni < FN; ++ni) {
            const int col = n0 + wc * SN + ni * 16 + l15;
            float bsum = 0.f;
            if constexpr (FUSE) bsum = bias[col];
            #pragma unroll
            for (int r = 0; r < 4; ++r) {
                const int row = rbase + r;
                float v = acc[mi][ni][r];
                if constexpr (FUSE) v += bsum + add[(size_t)seg[row] * PDIM + col];
                if constexpr (KSPLIT > 1)
                    atomicAdd(&C[(size_t)row * PDIM + col], v);
                else
                    C[(size_t)row * PDIM + col] = v;
            }
        }
    }
}

// ---------------------------------------------------------------------------
extern "C" void kernel_launch(void* const* d_in, const int* in_sizes, int n_in,
                              void* d_out, int out_size, void* d_ws, size_t ws_size,
                              hipStream_t stream)
{
    const float* x      = (const float*)d_in[0];
    const int*   label  = (const int*)d_in[1];
    const int*   lbatch = (const int*)d_in[2];
    const float* W1w    = (const float*)d_in[3];
    const float* W1b    = (const float*)d_in[4];
    const float* W2w    = (const float*)d_in[5];
    const float* W2b    = (const float*)d_in[6];
    float* out = (float*)d_out;

    char* ws = (char*)d_ws;
    size_t off = 0;
    auto alloc = [&](size_t bytes) {
        void* p = ws + off;
        off = (off + bytes + 255) & ~(size_t)255;
        return p;
    };
    unsigned short* xb   = (unsigned short*)alloc((size_t)N_SAMPLES * DIM * 2); // 67 MB
    unsigned short* sumb = (unsigned short*)alloc((size_t)NSEG * DIM * 2);      // 13 MB
    unsigned short* W1bf = (unsigned short*)alloc((size_t)PDIM * DIM * 2);
    unsigned short* W2bf = (unsigned short*)alloc((size_t)PDIM * DIM * 2);
    float* SW2    = (float*)alloc((size_t)NSEG * PDIM * 4);                     // 3.3 MB
    float* bias   = (float*)alloc(PDIM * 4);
    int*   seg    = (int*)alloc(N_SAMPLES * 4);
    int*   perm   = (int*)alloc(N_SAMPLES * 4);
    int*   offs   = (int*)alloc((NSEG + 1) * 4);
    int*   cursor = (int*)alloc(NSEG * 4);

    prep_kernel<<<PDIM * DIM / 256, 256, 0, stream>>>(
        W1w, W1b, W2w, W2b, label, lbatch, W1bf, W2bf, bias, seg, SW2);

    scan_kernel<<<1, 256, 0, stream>>>(seg, offs, cursor);
    scatter_kernel<<<N_SAMPLES / 256, 256, 0, stream>>>(seg, cursor, perm);

    segsum_kernel<<<dim3(DIM / 512, NSEG / 4), 256, 0, stream>>>(
        x, perm, offs, xb, sumb);

    // SW2[3200,256] = sum_bl @ W2^T : 32x256 tile, split-K=4, atomic f32 epilogue
    gemm_bt_kernel<32, 256, 1, 4, false, 4>
        <<<dim3(NSEG / 32, 1, 4), 256, 0, stream>>>(
        sumb, W2bf, SW2, nullptr, nullptr, nullptr, DIM);

    // SW2[s] <- (batch-total - SW2[s]) / dc   (LOO mean @ W2^T, by linearity)
    finalize_kernel<<<NB, 256, 0, stream>>>(SW2, offs);

    // out[16384,256] = x @ W1^T + bias + SW2[seg] : 64x128, 512 WGs = 2/CU
    gemm_bt_kernel<64, 128, 2, 2, true, 1>
        <<<dim3(N_SAMPLES / 64, PDIM / 128), 256, 0, stream>>>(
        xb, W1bf, out, bias, SW2, seg, DIM);
}

// Round 4
// 298.094 us; speedup vs baseline: 1.0871x; 1.0871x over previous
//
#include <hip/hip_runtime.h>
#include <cstdint>

#define N_SAMPLES 16384
#define DIM 2048
#define PDIM 256
#define NB 32
#define NL 100
#define NSEG (NB * NL)

typedef float floatx4 __attribute__((ext_vector_type(4)));
typedef __bf16 bf16x8 __attribute__((ext_vector_type(8)));

__device__ __forceinline__ unsigned short f32_to_bf16(float f) {
    unsigned int u = __float_as_uint(f);
    u += 0x7fffu + ((u >> 16) & 1u);   // round-to-nearest-even
    return (unsigned short)(u >> 16);
}
__device__ __forceinline__ unsigned int pack_bf16x2(float a, float b) {
    return (unsigned int)f32_to_bf16(a) | ((unsigned int)f32_to_bf16(b) << 16);
}

// ---------------------------------------------------------------------------
// prep: Wbf = [W1;W2] -> bf16 (512x2048), bias sum, seg index, zero cnt + SW2
// ---------------------------------------------------------------------------
__global__ __launch_bounds__(256) void prep_kernel(
    const float* __restrict__ W1w, const float* __restrict__ W1b,
    const float* __restrict__ W2w, const float* __restrict__ W2b,
    const int* __restrict__ label, const int* __restrict__ lbatch,
    unsigned short* __restrict__ Wbf, float* __restrict__ bias,
    int* __restrict__ seg, int* __restrict__ cnt, float* __restrict__ SW2)
{
    int i = blockIdx.x * 256 + threadIdx.x;   // grid = PDIM*DIM threads
    Wbf[i]              = f32_to_bf16(W1w[i]);
    Wbf[PDIM * DIM + i] = f32_to_bf16(W2w[i]);
    if (i < PDIM) bias[i] = W1b[i] + W2b[i];
    if (i < N_SAMPLES) seg[i] = lbatch[i] * NL + label[i];
    if (i < NSEG) cnt[i] = 0;
    if (i < NSEG * PDIM / 2) ((float2*)SW2)[i] = make_float2(0.f, 0.f);
}

__global__ __launch_bounds__(256) void hist_kernel(
    const int* __restrict__ seg, int* __restrict__ cnt)
{
    int i = blockIdx.x * 256 + threadIdx.x;
    atomicAdd(&cnt[seg[i]], 1);
}

// ---------------------------------------------------------------------------
// fused GEMM: A = x[16384,2048] f32 (reg-staged, converted to bf16 on the fly)
//             B = Wbf[512,2048] bf16 (global_load_lds), BM=64, BN=256, BK=32.
// grid = (2, 256): blockIdx.x==0 -> out[row,col] = x@W1^T + bias
//                  blockIdx.x==1 -> atomicAdd(SW2[seg[row],col], x@W2^T)
// By linearity, SW2[s] accumulates (sum over segment s of x) @ W2^T.
// Plain m97 2-barrier K-loop (known good); A-loads issued before the first
// barrier so HBM latency overlaps the barrier wait.
// ---------------------------------------------------------------------------
__global__ __launch_bounds__(256) void gemm_fused_kernel(
    const float* __restrict__ x, const unsigned short* __restrict__ Wbf,
    const float* __restrict__ bias, const int* __restrict__ seg,
    float* __restrict__ out, float* __restrict__ SW2)
{
    constexpr int BM = 64, BN = 256, BK = 32;
    __shared__ __align__(16) unsigned short ldsA[BM * BK];   // 4 KB
    __shared__ __align__(16) unsigned short ldsB[BN * BK];   // 16 KB
    const int tid = threadIdx.x;
    const int lane = tid & 63;
    const int wave = tid >> 6;                 // wave = wc (WR=1, WC=4)
    const int quad = lane >> 4, l15 = lane & 15;
    const int nhalf = blockIdx.x;              // 0: W1->out, 1: W2->SW2
    const int m0 = blockIdx.y * BM;
    const int srow = lane >> 2, schunk = lane & 3;
    const int arow = tid >> 2;                 // 0..63
    const int akc = (tid & 3) * 8;             // 0,8,16,24

    floatx4 acc[4][4];
    #pragma unroll
    for (int i = 0; i < 4; ++i)
        #pragma unroll
        for (int j = 0; j < 4; ++j) acc[i][j] = (floatx4){0.f, 0.f, 0.f, 0.f};

    const float* Ax = x + (size_t)(m0 + arow) * DIM + akc;
    const unsigned short* Bbase =
        Wbf + ((size_t)(nhalf * BN) + srow) * DIM + schunk * 8;

    for (int kk = 0; kk < DIM; kk += BK) {
        // A: 8 f32/thread, loads in flight across the barrier
        float4 a0 = *(const float4*)(Ax + kk);
        float4 a1 = *(const float4*)(Ax + kk + 4);
        __syncthreads();                       // all waves done reading prev tile
        uint4 ao;
        ao.x = pack_bf16x2(a0.x, a0.y);
        ao.y = pack_bf16x2(a0.z, a0.w);
        ao.z = pack_bf16x2(a1.x, a1.y);
        ao.w = pack_bf16x2(a1.z, a1.w);
        *(uint4*)&ldsA[arow * BK + akc] = ao;  // 16B/thread, conflict-free
        #pragma unroll
        for (int ch = wave; ch < BN / 16; ch += 4)
            __builtin_amdgcn_global_load_lds(
                (const __attribute__((address_space(1))) void*)(Bbase + (size_t)ch * 16 * DIM + kk),
                (__attribute__((address_space(3))) void*)&ldsB[ch * 16 * BK], 16, 0, 0);
        __syncthreads();                       // staging complete (vm+lgkm drained)

        bf16x8 af[4], bf[4];
        #pragma unroll
        for (int mi = 0; mi < 4; ++mi)
            af[mi] = *(const bf16x8*)&ldsA[(mi * 16 + l15) * BK + quad * 8];
        #pragma unroll
        for (int ni = 0; ni < 4; ++ni)
            bf[ni] = *(const bf16x8*)&ldsB[(wave * 64 + ni * 16 + l15) * BK + quad * 8];
        #pragma unroll
        for (int mi = 0; mi < 4; ++mi)
            #pragma unroll
            for (int ni = 0; ni < 4; ++ni)
                acc[mi][ni] = __builtin_amdgcn_mfma_f32_16x16x32_bf16(
                    af[mi], bf[ni], acc[mi][ni], 0, 0, 0);
    }

    if (nhalf == 0) {
        #pragma unroll
        for (int mi = 0; mi < 4; ++mi) {
            const int rbase = m0 + mi * 16 + quad * 4;
            #pragma unroll
            for (int ni = 0; ni < 4; ++ni) {
                const int col = wave * 64 + ni * 16 + l15;
                const float bs = bias[col];
                #pragma unroll
                for (int r = 0; r < 4; ++r)
                    out[(size_t)(rbase + r) * PDIM + col] = acc[mi][ni][r] + bs;
            }
        }
    } else {
        #pragma unroll
        for (int mi = 0; mi < 4; ++mi) {
            const int rbase = m0 + mi * 16 + quad * 4;
            #pragma unroll
            for (int r = 0; r < 4; ++r) {
                const int sr = seg[rbase + r];
                #pragma unroll
                for (int ni = 0; ni < 4; ++ni) {
                    const int col = wave * 64 + ni * 16 + l15;
                    atomicAdd(&SW2[(size_t)sr * PDIM + col], acc[mi][ni][r]);
                }
            }
        }
    }
}

// ---------------------------------------------------------------------------
// finalize: SW2[s,col] <- (BW2[b,col] - SW2[s,col]) / dc   (in place)
// BW2[b] = sum over the batch's 100 label-rows of SW2 (linearity),
// dc = batch count - segment count (zero-guarded like the reference).
// ---------------------------------------------------------------------------
__global__ __launch_bounds__(256) void finalize_kernel(
    float* __restrict__ SW2, const int* __restrict__ cnt)
{
    const int b = blockIdx.x;        // 0..31
    const int col = threadIdx.x;     // 0..255
    int cb = 0;
    #pragma unroll 4
    for (int l = 0; l < NL; ++l) cb += cnt[b * NL + l];
    float tot = 0.f;
    #pragma unroll 4
    for (int l = 0; l < NL; ++l)
        tot += SW2[(size_t)(b * NL + l) * PDIM + col];
    for (int l = 0; l < NL; ++l) {
        const int s = b * NL + l;
        const int dc = cb - cnt[s];
        const float v = SW2[(size_t)s * PDIM + col];
        SW2[(size_t)s * PDIM + col] = (dc > 0) ? (tot - v) / (float)dc : 0.f;
    }
}

// ---------------------------------------------------------------------------
// epilogue: out[i,:] += SW2[seg[i],:]   (float4 per thread)
// ---------------------------------------------------------------------------
__global__ __launch_bounds__(256) void epilogue_kernel(
    float* __restrict__ out, const float* __restrict__ SW2,
    const int* __restrict__ seg)
{
    const int idx = blockIdx.x * 256 + threadIdx.x;   // over N*PDIM/4
    const int row = idx >> 6;                         // 64 float4 per row
    const int c = (idx & 63) * 4;
    float4 v = ((const float4*)out)[idx];
    const float4 s4 = *(const float4*)&SW2[(size_t)seg[row] * PDIM + c];
    v.x += s4.x; v.y += s4.y; v.z += s4.z; v.w += s4.w;
    ((float4*)out)[idx] = v;
}

// ---------------------------------------------------------------------------
extern "C" void kernel_launch(void* const* d_in, const int* in_sizes, int n_in,
                              void* d_out, int out_size, void* d_ws, size_t ws_size,
                              hipStream_t stream)
{
    const float* x      = (const float*)d_in[0];
    const int*   label  = (const int*)d_in[1];
    const int*   lbatch = (const int*)d_in[2];
    const float* W1w    = (const float*)d_in[3];
    const float* W1b    = (const float*)d_in[4];
    const float* W2w    = (const float*)d_in[5];
    const float* W2b    = (const float*)d_in[6];
    float* out = (float*)d_out;

    char* ws = (char*)d_ws;
    size_t off = 0;
    auto alloc = [&](size_t bytes) {
        void* p = ws + off;
        off = (off + bytes + 255) & ~(size_t)255;
        return p;
    };
    unsigned short* Wbf = (unsigned short*)alloc((size_t)2 * PDIM * DIM * 2);  // 2 MB
    float* SW2  = (float*)alloc((size_t)NSEG * PDIM * 4);                      // 3.3 MB
    float* bias = (float*)alloc(PDIM * 4);
    int*   seg  = (int*)alloc(N_SAMPLES * 4);
    int*   cnt  = (int*)alloc(NSEG * 4);

    prep_kernel<<<PDIM * DIM / 256, 256, 0, stream>>>(
        W1w, W1b, W2w, W2b, label, lbatch, Wbf, bias, seg, cnt, SW2);

    hist_kernel<<<N_SAMPLES / 256, 256, 0, stream>>>(seg, cnt);

    // out = x@W1^T + bias ; SW2[s] += (x@W2^T rows of segment s)
    gemm_fused_kernel<<<dim3(2, N_SAMPLES / 64), 256, 0, stream>>>(
        x, Wbf, bias, seg, out, SW2);

    // SW2[s] <- (batch-total - SW2[s]) / dc   (LOO mean @ W2^T, by linearity)
    finalize_kernel<<<NB, 256, 0, stream>>>(SW2, cnt);

    // out += SW2[seg]
    epilogue_kernel<<<(size_t)N_SAMPLES * PDIM / 4 / 256, 256, 0, stream>>>(
        out, SW2, seg);
}